// Round 7
// baseline (50.308 us; speedup 1.0000x reference)
//
#include <hip/hip_runtime.h>
#include <hip/hip_bf16.h>

typedef __attribute__((ext_vector_type(8))) short short8;
typedef __attribute__((ext_vector_type(4))) float f32x4;

#define N_ENS 16
#define D_IN 784
#define D_HID 128
#define D_OUT 10
#define NKT 25            // K tiles of 32 (784 padded to 800)
#define TILE_B 8192       // 128 cols x 32 k x 2B (bf16), fragment-packed + swizzled
#define WS_B1 204800      // NKT*8192
#define WS_W2 205312      // + 128*4   (w2 stored [10][128] f32)
#define WS_B2 210432      // + 1280*4

// RNE float->bf16 (inputs are finite)
__device__ __forceinline__ unsigned short f2bf(float f) {
  unsigned int u = __float_as_uint(f);
  return (unsigned short)((u + 0x7FFFu + ((u >> 16) & 1u)) >> 16);
}

__device__ __forceinline__ void gload_lds16(const void* g, void* l) {
  __builtin_amdgcn_global_load_lds((const __attribute__((address_space(1))) void*)g,
                                   (__attribute__((address_space(3))) void*)l, 16, 0, 0);
}

// Swizzled byte offset of frag granule (col c, k-granule kg) within one 8KB tile.
__device__ __forceinline__ int bswz(int c, int kg) {
  return ((c >> 1) << 7) + (((((c & 1) << 2) | kg) ^ ((c >> 1) & 7)) << 4);
}

// ---------------- prep: combine ensemble -> ws (vectorized over k) ----------------
__global__ void prep_kernel(const float* __restrict__ fc_w, const float* __restrict__ fc_b,
                            const float* __restrict__ cls_w, const float* __restrict__ cls_b,
                            const float* __restrict__ factor, char* __restrict__ ws) {
  int tid = blockIdx.x * 256 + threadIdx.x;
  float f[N_ENS];
#pragma unroll
  for (int e = 0; e < N_ENS; ++e) f[e] = factor[e];

  if (tid < 25600) {                              // w1: 128 cols x 200 k-quads
    int col = tid / 200;
    int kq  = tid - col * 200;
    int k   = kq * 4;
    float4 v = float4{0.f, 0.f, 0.f, 0.f};
    if (k + 3 < D_IN) {
#pragma unroll
      for (int e = 0; e < N_ENS; ++e) {
        const float4 t = *(const float4*)(fc_w + (size_t)(e * D_HID + col) * D_IN + k);
        v.x += f[e] * t.x; v.y += f[e] * t.y; v.z += f[e] * t.z; v.w += f[e] * t.w;
      }
    }
    const int kt = k >> 5, kg = (k & 31) >> 3, half = k & 7;   // half in {0,4}
    union { unsigned short u[4]; uint2 p; } pk;
    pk.u[0] = f2bf(v.x); pk.u[1] = f2bf(v.y); pk.u[2] = f2bf(v.z); pk.u[3] = f2bf(v.w);
    *(uint2*)(ws + kt * TILE_B + bswz(col, kg) + half * 2) = pk.p;
  } else if (tid < 25600 + D_HID) {               // b1
    int col = tid - 25600;
    float v = 0.f;
#pragma unroll
    for (int e = 0; e < N_ENS; ++e) v += f[e] * fc_b[e * D_HID + col];
    *(float*)(ws + WS_B1 + col * 4) = v;
  } else if (tid < 25600 + D_HID + D_HID * D_OUT) {  // w2o[o][n]
    int i = tid - (25600 + D_HID);
    int o = i >> 7, n = i & 127;
    float v = 0.f;
#pragma unroll
    for (int e = 0; e < N_ENS; ++e) v += f[e] * cls_w[(e * D_OUT + o) * D_HID + n];
    *(float*)(ws + WS_W2 + i * 4) = v;
  } else if (tid < 25600 + D_HID + D_HID * D_OUT + D_OUT) {  // b2
    int o = tid - (25600 + D_HID + D_HID * D_OUT);
    float v = 0.f;
#pragma unroll
    for (int e = 0; e < N_ENS; ++e) v += f[e] * cls_b[e * D_OUT + o];
    *(float*)(ws + WS_B2 + o * 4) = v;
  }
}

// ---------------- main: 2-iteration-deep pipeline on BOTH streams ----------------
// 256 thr = 4 waves (4x1 grid): wave w owns rows m0+w*16..+16, all 128 cols.
// A: global f32 -> 2 register sets (loaded kt+2 ahead) -> bf16.
// B: global_load_lds into 3 rotating LDS bufs (staged kt+2 ahead).
// Per iter: one counted vmcnt(4) (drains exactly tile-kt's loads, issued 2 iters ago).
#define SB __builtin_amdgcn_sched_barrier(0)
#define ROT(o) o = ((o) == 16384) ? 0 : (o) + 8192

__global__ __launch_bounds__(256, 4) void mnist_fused(const float* __restrict__ x,
                                                      const char* __restrict__ ws,
                                                      float* __restrict__ out) {
  // LDS: 3 B-bufs @0..24K; epilogue reuse: h f32 [64][132] @0 (33792B), w2s @33792 (5120B)
  __shared__ __align__(16) char smem[38912];
  const int tid  = threadIdx.x;
  const int lane = tid & 63;
  const int w    = tid >> 6;
  const int l15  = lane & 15;
  const int kg   = lane >> 4;
  const int m0   = blockIdx.x * 64;

  const float* ar = x + (size_t)(m0 + w * 16 + l15) * D_IN;  // this lane's A row
  int boff[8];                                               // swizzled B frag offsets
#pragma unroll
  for (int ni = 0; ni < 8; ++ni) boff[ni] = bswz(ni * 16 + l15, kg);

  f32x4 acc[8];
#pragma unroll
  for (int ni = 0; ni < 8; ++ni) acc[ni] = f32x4{0.f, 0.f, 0.f, 0.f};

  // ---- prologue: stage B(0)->buf0, B(1)->buf1; A(0)->setA, A(1)->setB
  gload_lds16(ws + w * 2048 + lane * 16,                 smem + w * 2048);
  gload_lds16(ws + w * 2048 + 1024 + lane * 16,          smem + w * 2048 + 1024);
  gload_lds16(ws + TILE_B + w * 2048 + lane * 16,        smem + 8192 + w * 2048);
  gload_lds16(ws + TILE_B + w * 2048 + 1024 + lane * 16, smem + 8192 + w * 2048 + 1024);
  float4 aA0 = *(const float4*)(ar + kg * 8);
  float4 aA1 = *(const float4*)(ar + kg * 8 + 4);
  float4 aB0 = *(const float4*)(ar + 32 + kg * 8);
  float4 aB1 = *(const float4*)(ar + 32 + kg * 8 + 4);

  int rdoff = 0, wroff = 16384;

#define ITER(kt, A0v, A1v) do {                                               \
    if ((kt) < 23) { SB; asm volatile("s_waitcnt vmcnt(4)" ::: "memory"); SB; }\
    else           { SB; asm volatile("s_waitcnt vmcnt(0)" ::: "memory"); SB; }\
    __builtin_amdgcn_s_barrier();  /* B1: tile kt resident in buf rdoff */     \
    SB;                                                                        \
    if ((kt) + 2 < NKT) {  /* stage B(kt+2) into buf wroff */                  \
      const char* src = ws + ((kt) + 2) * TILE_B + w * 2048;                   \
      char* dst = smem + wroff + w * 2048;                                     \
      gload_lds16(src + lane * 16, dst);                                       \
      gload_lds16(src + 1024 + lane * 16, dst + 1024);                         \
    }                                                                          \
    union { unsigned short u[8]; short8 s; } pk;   /* convert A(kt) */         \
    pk.u[0]=f2bf(A0v.x); pk.u[1]=f2bf(A0v.y); pk.u[2]=f2bf(A0v.z); pk.u[3]=f2bf(A0v.w); \
    pk.u[4]=f2bf(A1v.x); pk.u[5]=f2bf(A1v.y); pk.u[6]=f2bf(A1v.z); pk.u[7]=f2bf(A1v.w); \
    if ((kt) + 2 < NKT) {  /* issue A(kt+2) into the set just consumed */      \
      if ((kt) + 2 < 24 || kg < 2) {                                           \
        A0v = *(const float4*)(ar + ((kt) + 2) * 32 + kg * 8);                 \
        A1v = *(const float4*)(ar + ((kt) + 2) * 32 + kg * 8 + 4);             \
      } else {                                                                 \
        A0v = float4{0.f, 0.f, 0.f, 0.f};                                      \
        A1v = float4{0.f, 0.f, 0.f, 0.f};                                      \
      }                                                                        \
    }                                                                          \
    {                                                                          \
      const char* Bb = smem + rdoff;                                           \
      short8 b[8];                                                             \
      _Pragma("unroll") for (int ni = 0; ni < 8; ++ni)                         \
        b[ni] = *(const short8*)(Bb + boff[ni]);                               \
      _Pragma("unroll") for (int ni = 0; ni < 8; ++ni)                         \
        acc[ni] = __builtin_amdgcn_mfma_f32_16x16x32_bf16(pk.s, b[ni], acc[ni], 0, 0, 0); \
    }                                                                          \
    SB;                                                                        \
    __builtin_amdgcn_s_barrier();  /* B2: buf rdoff consumed */                \
    SB;                                                                        \
    ROT(rdoff); ROT(wroff);                                                    \
  } while (0)

  for (int kt = 0; kt < 24; kt += 2) {
    ITER(kt,     aA0, aA1);
    ITER(kt + 1, aB0, aB1);
  }
  ITER(24, aA0, aA1);
#undef ITER

  __syncthreads();   // protect staging region before reusing it as h

  // ---- epilogue 1: h = relu(acc + b1) -> LDS (rows w*16+kg*4+j, wave-exclusive)
  const float* b1g = (const float*)(ws + WS_B1);
  float (*h)[132] = (float (*)[132])smem;
#pragma unroll
  for (int ni = 0; ni < 8; ++ni) {
    const float bv = b1g[ni * 16 + l15];
#pragma unroll
    for (int j = 0; j < 4; ++j) {
      float v = acc[ni][j] + bv;
      h[w * 16 + kg * 4 + j][ni * 16 + l15] = v > 0.f ? v : 0.f;
    }
  }
  // stage w2 -> LDS (region disjoint from h), then full sync
  float* w2s = (float*)(smem + 33792);
  {
    const float* w2g = (const float*)(ws + WS_W2);
    for (int i = tid; i < 1280; i += 256) w2s[i] = w2g[i];
  }
  __syncthreads();

  // ---- epilogue 2: out = h @ w2^T + b2; lane: row w*16+l15, n-quarter kg
  const int row = w * 16 + l15;
  float po[10];
#pragma unroll
  for (int o = 0; o < 10; ++o) po[o] = 0.f;
#pragma unroll
  for (int n4 = 0; n4 < 8; ++n4) {
    const float4 hv = *(const float4*)(&h[row][kg * 32 + n4 * 4]);
#pragma unroll
    for (int o = 0; o < 10; ++o) {
      const float4 wv = *(const float4*)(w2s + o * 128 + kg * 32 + n4 * 4);
      po[o] += hv.x * wv.x + hv.y * wv.y + hv.z * wv.z + hv.w * wv.w;
    }
  }
#pragma unroll
  for (int o = 0; o < 10; ++o) {
    po[o] += __shfl_xor(po[o], 16);
    po[o] += __shfl_xor(po[o], 32);
  }
  if (kg == 0) {
    const float* b2g = (const float*)(ws + WS_B2);
    float* op = out + (size_t)(m0 + row) * 10;
#pragma unroll
    for (int o = 0; o < 10; o += 2) {
      float2 v;
      v.x = po[o]     + b2g[o];
      v.y = po[o + 1] + b2g[o + 1];
      *(float2*)(op + o) = v;
    }
  }
}

extern "C" void kernel_launch(void* const* d_in, const int* in_sizes, int n_in,
                              void* d_out, int out_size, void* d_ws, size_t ws_size,
                              hipStream_t stream) {
  const float* x      = (const float*)d_in[0];
  const float* fc_w   = (const float*)d_in[1];
  const float* fc_b   = (const float*)d_in[2];
  const float* cls_w  = (const float*)d_in[3];
  const float* cls_b  = (const float*)d_in[4];
  const float* factor = (const float*)d_in[5];
  char* ws = (char*)d_ws;
  float* outp = (float*)d_out;

  prep_kernel<<<106, 256, 0, stream>>>(fc_w, fc_b, cls_w, cls_b, factor, ws);
  mnist_fused<<<1024, 256, 0, stream>>>(x, ws, outp);
}